// Round 14
// baseline (110.480 us; speedup 1.0000x reference)
//
#include <hip/hip_runtime.h>
#include <math.h>

#define S_LEN 2048
#define DMODEL 1024
#define NHEAD 16
#define DHEAD 64
#define WIN 128
#define NQKV 1152

typedef _Float16 f16x8 __attribute__((ext_vector_type(8)));
typedef float f32x4 __attribute__((ext_vector_type(4)));

__device__ __forceinline__ ushort f2h(float f) {
  union { _Float16 h; ushort u; } v; v.h = (_Float16)f; return v.u;
}

typedef __attribute__((address_space(1))) const unsigned GU;
typedef __attribute__((address_space(3))) unsigned LU;
__device__ __forceinline__ void async16(const ushort* g, ushort* l) {
  __builtin_amdgcn_global_load_lds((GU*)g, (LU*)l, 16, 0, 0);
}

// ---------------------------------------------------------------- 32x64 f16 GEMM (R7/R11/R13-verified schedule)
// 2-deep dbuf, prefetch issued BEFORE compute, plain __syncthreads per K-tile — the only
// schedule that wins here. XCD rectangle map (R13, neutral-but-free). MODE 1 (QKV GEMM)
// now stages DIRECTLY FROM F32 x/Wqkv with in-flight f16 conversion — the convert
// dispatch is deleted entirely (T14 issue-early/write-late: f32 loads for tile kt+1
// issue before tile kt's MFMA, cvt+ds_write land after, before the barrier). Reg-staging
// writes the XOR chunk swizzle natively: lane l of wave w writes row 8*<grp>+ (l>>3),
// slot l&7, holding global chunk (l&7)^(l>>3) — identical LDS image to the async16
// path, so the ds_read side is unchanged. q-row x8 scale folds into the pre-cvt
// multiply (8-row groups never straddle the 128 boundary). MODE 0 (out GEMM) keeps the
// verified async16 f16 path (obuf/wo16 are f16).
// 4 waves; wave w computes rows m0..m0+32 x cols n0+16w..n0+16w+16. acc[2].
// C[M][N] = A[M][K] * B[N][K]^T + bias. MODE 0: fp32 out. MODE 1: qkv epilogue ->
// k16[S][64] f16, vT[64][S] f16 (transposed!), q16[S][1024] f16 (bias x8 on q cols).
template<int MODE>
__global__ __launch_bounds__(256)
void gemm32(const ushort* __restrict__ A16, const ushort* __restrict__ B16,
            const float* __restrict__ A32, const float* __restrict__ B32,
            const float* __restrict__ bias, float* __restrict__ Cout,
            ushort* __restrict__ k16, ushort* __restrict__ vT, ushort* __restrict__ q16,
            int M, int N, int K) {
  __shared__ __align__(16) ushort sA[2][32 * 64];    // 2 x 4 KiB
  __shared__ __align__(16) ushort sB[2][64 * 64];    // 2 x 8 KiB  (total 24 KiB)
  const int t = threadIdx.x;
  const int w = t >> 6, lane = t & 63;
  const int quad = lane >> 4, l16 = lane & 15;
  const int wn = w * 16;

  // XCD rectangle mapping (bijective; 64 m-tiles split 4 m-groups x 2 n-groups)
  const int bid = blockIdx.x;
  const int half = (N >> 6) >> 1;            // n-tiles per n-group: 9 (gemm1) or 8 (gemm2)
  const int xcd = bid & 7, l = bid >> 3;
  const int mg = xcd >> 1, ng = xcd & 1;
  const int m0 = (mg * 16 + (l & 15)) * 32;
  const int n0 = (ng * half + (l >> 4)) * 64;

  // staging geometry: 8-row groups; lane l covers row (l>>3), 16B slot (l&7),
  // global chunk c = (l&7)^(l>>3) (XOR chunk swizzle, row ≡ l>>3 mod 8).
  const int lr = lane >> 3;
  const int lc = (lane & 7) ^ lr;
  const size_t aBase = (size_t)(m0 + 8 * w + lr) * K + lc * 8;   // wave stages 8 A-rows
  const size_t bBase = (size_t)(n0 + 16 * w + lr) * K + lc * 8;  // wave stages 16 B-rows

  f32x4 acc[2] = {};
  const int NT = K >> 6;   // 16

  if (MODE == 0) {
    // ---------------- f16 async16 staging (verified path)
    auto STAGE = [&](int ktile, int b) {
      const size_t koff = (size_t)ktile << 6;
      async16(A16 + aBase + koff, &sA[b][(8 * w) * 64]);
#pragma unroll
      for (int i = 0; i < 2; ++i)
        async16(B16 + bBase + (size_t)(8 * i) * K + koff, &sB[b][(16 * w + 8 * i) * 64]);
    };
    STAGE(0, 0);
    __syncthreads();
    for (int kt = 0; kt < NT; ++kt) {
      const int cur = kt & 1;
      if (kt + 1 < NT) STAGE(kt + 1, cur ^ 1);
      f16x8 af[2][2], bf[2];
#pragma unroll
      for (int kst = 0; kst < 2; ++kst) {
        const int cp = ((kst << 2) | quad) ^ (l16 & 7);
#pragma unroll
        for (int i = 0; i < 2; ++i)
          af[kst][i] = *(const f16x8*)(&sA[cur][(16 * i + l16) * 64 + cp * 8]);
        bf[kst] = *(const f16x8*)(&sB[cur][(wn + l16) * 64 + cp * 8]);
      }
#pragma unroll
      for (int kst = 0; kst < 2; ++kst)
#pragma unroll
        for (int i = 0; i < 2; ++i)
          acc[i] = __builtin_amdgcn_mfma_f32_16x16x32_f16(af[kst][i], bf[kst], acc[i], 0, 0, 0);
      __syncthreads();
    }
  } else {
    // ---------------- f32 reg-staging with in-flight conversion (convert dispatch deleted)
    // Per wave per tile: A 8 rows (1 group), B 16 rows (2 groups). Lane loads 8 f32
    // per group (2 dwordx4), converts, writes one f16x8 to the swizzled slot.
    const float bsc0 = (n0 + 16 * w + lr >= 2 * DHEAD) ? 8.0f : 1.0f;       // B group 0
    const float bsc1 = (n0 + 16 * w + 8 + lr >= 2 * DHEAD) ? 8.0f : 1.0f;   // B group 1
    float4 ra[2], rb0[2], rb1[2];
    auto LOAD = [&](int ktile) {
      const size_t koff = (size_t)ktile << 6;
      ra[0]  = *(const float4*)(A32 + aBase + koff);
      ra[1]  = *(const float4*)(A32 + aBase + koff + 4);
      rb0[0] = *(const float4*)(B32 + bBase + koff);
      rb0[1] = *(const float4*)(B32 + bBase + koff + 4);
      rb1[0] = *(const float4*)(B32 + bBase + (size_t)8 * K + koff);
      rb1[1] = *(const float4*)(B32 + bBase + (size_t)8 * K + koff + 4);
    };
    auto CVT = [&](const float4* r, float s) -> f16x8 {
      f16x8 h;
      h[0] = (_Float16)(r[0].x * s); h[1] = (_Float16)(r[0].y * s);
      h[2] = (_Float16)(r[0].z * s); h[3] = (_Float16)(r[0].w * s);
      h[4] = (_Float16)(r[1].x * s); h[5] = (_Float16)(r[1].y * s);
      h[6] = (_Float16)(r[1].z * s); h[7] = (_Float16)(r[1].w * s);
      return h;
    };
    auto WRITE = [&](int b) {
      *(f16x8*)(&sA[b][(8 * w + lr) * 64 + (lane & 7) * 8])        = CVT(ra, 1.0f);
      *(f16x8*)(&sB[b][(16 * w + lr) * 64 + (lane & 7) * 8])       = CVT(rb0, bsc0);
      *(f16x8*)(&sB[b][(16 * w + 8 + lr) * 64 + (lane & 7) * 8])   = CVT(rb1, bsc1);
    };
    LOAD(0);
    WRITE(0);
    __syncthreads();
    for (int kt = 0; kt < NT; ++kt) {
      const int cur = kt & 1;
      if (kt + 1 < NT) LOAD(kt + 1);    // issue-early: f32 loads fly during MFMA phase
      f16x8 af[2][2], bf[2];
#pragma unroll
      for (int kst = 0; kst < 2; ++kst) {
        const int cp = ((kst << 2) | quad) ^ (l16 & 7);
#pragma unroll
        for (int i = 0; i < 2; ++i)
          af[kst][i] = *(const f16x8*)(&sA[cur][(16 * i + l16) * 64 + cp * 8]);
        bf[kst] = *(const f16x8*)(&sB[cur][(wn + l16) * 64 + cp * 8]);
      }
#pragma unroll
      for (int kst = 0; kst < 2; ++kst)
#pragma unroll
        for (int i = 0; i < 2; ++i)
          acc[i] = __builtin_amdgcn_mfma_f32_16x16x32_f16(af[kst][i], bf[kst], acc[i], 0, 0, 0);
      if (kt + 1 < NT) WRITE(cur ^ 1);  // write-late: after this tile's reads, pre-barrier
      __syncthreads();
    }
  }

  const int cb = n0 + wn;               // lane-uniform column base
  const int col = cb + l16;
#pragma unroll
  for (int i = 0; i < 2; ++i) {
    if (MODE == 0) {
      const float b = bias[col];
#pragma unroll
      for (int r = 0; r < 4; ++r) {
        const int row = m0 + 16 * i + quad * 4 + r;
        Cout[(size_t)row * N + col] = acc[i][r] + b;
      }
    } else {
      const float bscale = (cb >= 2 * DHEAD) ? 8.0f : 1.0f;
      const float b = bias[col] * bscale;
#pragma unroll
      for (int r = 0; r < 4; ++r) {
        const int row = m0 + 16 * i + quad * 4 + r;
        const ushort h = f2h(acc[i][r] + b);
        if (cb >= 2 * DHEAD) {
          q16[(size_t)row * DMODEL + (col - 2 * DHEAD)] = h;
        } else if (cb < DHEAD) {
          k16[(size_t)row * DHEAD + col] = h;
        } else {
          vT[(size_t)(col - DHEAD) * S_LEN + row] = h;
        }
      }
    }
  }
}

// ---------------------------------------------------------------- MFMA flash attention (f16)
// R13-verified body (R7 attn + fused Wout conversion riding the cold K-stage latency
// shadow). QT=4: one query per wave, 512 blocks, LDS 45 KiB. Key window
// [jbase, jbase+160), jbase=(i0-127)&~7 (clamped 0); max span 138 <= 160. Keys >=
// S_LEN read allocated slack and are masked (exp(-1e30)=0). LDS: Ksw[160][64]
// (chunk-swizzled, global_load_lds), aliased after QK^T by P[64][176]; Vt[64][176].
#define QT 4
#define NTK 10
#define KST 5
#define PSTR 176

__global__ __launch_bounds__(256)
void attn_kernel(const ushort* __restrict__ k16, const ushort* __restrict__ vT,
                 const ushort* __restrict__ q16, ushort* __restrict__ obuf,
                 const float4* __restrict__ wo, ushort4* __restrict__ wo16) {
  __shared__ __align__(16) ushort lds[64 * PSTR + 64 * PSTR];  // 45,056 B
  ushort* Ksw = lds;                  // [160][64] = 20,480 B (inside P region)
  ushort* P   = lds;                  // [64][176] = 22,528 B
  ushort* Vt  = lds + 64 * PSTR;      // [64][176] = 22,528 B

  const int t = threadIdx.x;
  const int i0 = blockIdx.x * QT;
  const int jbase = (i0 >= WIN - 1) ? ((i0 - (WIN - 1)) & ~7) : 0;
  const int w = t >> 6, lane = t & 63;
  const int quad = lane >> 4, l16 = lane & 15;
  const int qg = i0 + w;              // this wave's query

  // ---- stage K: 20 async 1KB instrs, XOR chunk swizzle (chunk c of row r at slot c^(r&7))
#pragma unroll
  for (int i = 0; i < 5; ++i) {
    const int n = 5 * w + i;                 // 0..19, 8 rows each
    const int r = 8 * n + (lane >> 3);
    const int cs = (lane & 7) ^ (r & 7);
    async16(k16 + (size_t)(jbase + r) * DHEAD + cs * 8, &Ksw[n * 512]);
  }
  // ---- fused Wout conversion: 2 float4/thread, overlaps the cold K-stage latency
  {
    const int base = blockIdx.x * 512 + t;   // 512 float4 per block, 262144 total
#pragma unroll
    for (int u = 0; u < 2; ++u) {
      const int idx = base + u * 256;
      const float4 v = wo[idx];
      ushort4 h; h.x = f2h(v.x); h.y = f2h(v.y); h.z = f2h(v.z); h.w = f2h(v.w);
      wo16[idx] = h;
    }
  }
  // ---- stage Vt[64][160] from vT (16B aligned since jbase%8==0)
  {
    const int d = t >> 2, p = t & 3;
#pragma unroll
    for (int it = 0; it < 5; ++it) {
      const int c = p + 4 * it;              // 0..19
      const uint4 raw = *(const uint4*)(vT + (size_t)d * S_LEN + jbase + c * 8);
      *(uint4*)(&Vt[d * PSTR + c * 8]) = raw;
    }
  }
  // ---- Q fragments: lane m-row = head = l16
  f16x8 qf[2];
  {
    const size_t qbase = (size_t)qg * DMODEL + l16 * DHEAD;
#pragma unroll
    for (int kst = 0; kst < 2; ++kst)
      qf[kst] = *(const f16x8*)(q16 + qbase + kst * 32 + quad * 8);
  }
  __syncthreads();

  // ---- QK^T: acc[nt], rows=heads (quad*4+r), cols=keys (nt*16+l16)
  f32x4 acc[NTK] = {};
#pragma unroll
  for (int nt = 0; nt < NTK; ++nt) {
#pragma unroll
    for (int kst = 0; kst < 2; ++kst) {
      const int cp = ((kst << 2) | quad) ^ (l16 & 7);
      const f16x8 bf = *(const f16x8*)(&Ksw[(nt * 16 + l16) * 64 + cp * 8]);
      acc[nt] = __builtin_amdgcn_mfma_f32_16x16x32_f16(qf[kst], bf, acc[nt], 0, 0, 0);
    }
  }
  __syncthreads();  // K region dead; Vt stores drained

  // ---- mask + softmax (regs/shfl over 16 lanes), P -> LDS f16
  float inv_l[4];
#pragma unroll
  for (int nt = 0; nt < NTK; ++nt) {
    const int jg = jbase + nt * 16 + l16;
    const bool valid = (jg <= qg) && (jg > qg - WIN);
#pragma unroll
    for (int r = 0; r < 4; ++r)
      if (!valid) acc[nt][r] = -1e30f;
  }
#pragma unroll
  for (int r = 0; r < 4; ++r) {
    float m = acc[0][r];
#pragma unroll
    for (int nt = 1; nt < NTK; ++nt) m = fmaxf(m, acc[nt][r]);
#pragma unroll
    for (int off = 1; off < 16; off <<= 1) m = fmaxf(m, __shfl_xor(m, off));
    float s = 0.f;
#pragma unroll
    for (int nt = 0; nt < NTK; ++nt) {
      const float e = __expf(acc[nt][r] - m);
      acc[nt][r] = e;
      s += e;
    }
#pragma unroll
    for (int off = 1; off < 16; off <<= 1) s += __shfl_xor(s, off);
    inv_l[r] = 1.0f / s;
  }
  {
    const int mrow0 = w * 16 + quad * 4;
#pragma unroll
    for (int r = 0; r < 4; ++r)
#pragma unroll
      for (int nt = 0; nt < NTK; ++nt)
        P[(mrow0 + r) * PSTR + nt * 16 + l16] = f2h(acc[nt][r]);
  }
  __syncthreads();

  // ---- PV: o[nd], rows=heads, cols=d (nd*16+l16); 5 K-steps over 160 keys
  f32x4 o[4] = {};
#pragma unroll
  for (int kst = 0; kst < KST; ++kst) {
    const f16x8 a = *(const f16x8*)(&P[(w * 16 + l16) * PSTR + kst * 32 + quad * 8]);
#pragma unroll
    for (int nd = 0; nd < 4; ++nd) {
      const f16x8 b = *(const f16x8*)(&Vt[(nd * 16 + l16) * PSTR + kst * 32 + quad * 8]);
      o[nd] = __builtin_amdgcn_mfma_f32_16x16x32_f16(a, b, o[nd], 0, 0, 0);
    }
  }

  // ---- epilogue: normalize, write obuf f16
  {
    const size_t obase = (size_t)qg * DMODEL;
#pragma unroll
    for (int nd = 0; nd < 4; ++nd)
#pragma unroll
      for (int r = 0; r < 4; ++r) {
        const int col = (quad * 4 + r) * DHEAD + nd * 16 + l16;
        obuf[obase + col] = f2h(o[nd][r] * inv_l[r]);
      }
  }
}

// ---------------------------------------------------------------- launch (3 dispatches)
extern "C" void kernel_launch(void* const* d_in, const int* in_sizes, int n_in,
                              void* d_out, int out_size, void* d_ws, size_t ws_size,
                              hipStream_t stream) {
  const float* x    = (const float*)d_in[0];
  const float* Wqkv = (const float*)d_in[1];
  const float* bqkv = (const float*)d_in[2];
  const float* Wout = (const float*)d_in[3];
  const float* bout = (const float*)d_in[4];
  float* out = (float*)d_out;

  char* w = (char*)d_ws;
  ushort* wo16 = (ushort*)(w + 6553600);    // 2,097,152 B
  ushort* k16  = (ushort*)(w + 8650752);    // 270,336 B  (2112 rows x 64; rows >=2048 stay 0xAA)
  ushort* vT   = (ushort*)(w + 8921088);    // 270,336 B  (64 x 2048 + 8KB slack, stays 0xAA)
  ushort* q16  = (ushort*)(w + 9191424);    // 4,194,304 B
  ushort* obuf = (ushort*)(w + 13385728);   // 4,194,304 B

  // gemm1: stages f32 x/Wqkv directly (convert dispatch deleted)
  gemm32<1><<<1152, 256, 0, stream>>>(nullptr, nullptr, x, Wqkv, bqkv, nullptr,
                                      k16, vT, q16, S_LEN, NQKV, DMODEL);

  attn_kernel<<<S_LEN / QT, 256, 0, stream>>>(k16, vT, q16, obuf,
                                              (const float4*)Wout, (ushort4*)wo16);

  gemm32<0><<<1024, 256, 0, stream>>>(obuf, wo16, nullptr, nullptr, bout, out,
                                      nullptr, nullptr, nullptr, S_LEN, DMODEL, DMODEL);
}

// Round 15
// 104.387 us; speedup vs baseline: 1.0584x; 1.0584x over previous
//
#include <hip/hip_runtime.h>
#include <math.h>

#define S_LEN 2048
#define DMODEL 1024
#define NHEAD 16
#define DHEAD 64
#define WIN 128
#define NQKV 1152

typedef _Float16 f16x8 __attribute__((ext_vector_type(8)));
typedef float f32x4 __attribute__((ext_vector_type(4)));

__device__ __forceinline__ ushort f2h(float f) {
  union { _Float16 h; ushort u; } v; v.h = (_Float16)f; return v.u;
}

typedef __attribute__((address_space(1))) const unsigned GU;
typedef __attribute__((address_space(3))) unsigned LU;
__device__ __forceinline__ void async16(const ushort* g, ushort* l) {
  __builtin_amdgcn_global_load_lds((GU*)g, (LU*)l, 16, 0, 0);
}

// ---------------------------------------------------------------- convert fp32 -> f16 (x, Wqkv only)
// Wout conversion lives in attn_kernel's prologue (R11). R14's f32-staging gemm1
// (convert deleted) regressed +5us: reg-staging put vmcnt waits + cvt VALU on the
// K-loop critical path. The separate convert dispatch is the verified optimum.
__global__ __launch_bounds__(256)
void convert_kernel(const float4* __restrict__ x, const float4* __restrict__ wq,
                    ushort4* __restrict__ x16, ushort4* __restrict__ w16) {
  const int NX4 = (S_LEN * DMODEL) / 4;       // 524288
  const int i = blockIdx.x * 256 + threadIdx.x;
  if (i < NX4) {
    const float4 v = x[i];
    ushort4 h; h.x = f2h(v.x); h.y = f2h(v.y); h.z = f2h(v.z); h.w = f2h(v.w);
    x16[i] = h;
  } else {
    const int j = i - NX4;                    // < 294912 by grid sizing
    const float s = ((j >> 8) >= 2 * DHEAD) ? 8.0f : 1.0f;  // fold sqrt(D) into q-rows
    const float4 v = wq[j];
    ushort4 h; h.x = f2h(v.x * s); h.y = f2h(v.y * s); h.z = f2h(v.z * s); h.w = f2h(v.w * s);
    w16[j] = h;
  }
}

// ---------------------------------------------------------------- 32x64 f16 GEMM (R13-verified)
// 2-deep dbuf, prefetch issued BEFORE compute, plain __syncthreads per K-tile — the
// only schedule that wins here (counted-vmcnt x2, B-in-regs, 32x32 tiles, f32
// reg-staging all regressed). XCD rectangle map (R13): each XCD gets a contiguous
// 4x2 sub-rectangle of the tile grid for per-L2 working-set locality (neutral-but-free).
// XOR chunk swizzle: LDS dest linear (global_load_lds req), global source chunk
// pre-swizzled by (lane&7)^(row&7); ds_read applies the same involution.
// 4 waves; wave w computes rows m0..m0+32 x cols n0+16w..n0+16w+16. acc[2].
// C[M][N] = A[M][K] * B[N][K]^T + bias. MODE 0: fp32 out. MODE 1: qkv epilogue ->
// k16[S][64] f16, vT[64][S] f16 (transposed!), q16[S][1024] f16 (bias x8 on q cols).
template<int MODE>
__global__ __launch_bounds__(256)
void gemm32(const ushort* __restrict__ A, const ushort* __restrict__ B,
            const float* __restrict__ bias, float* __restrict__ Cout,
            ushort* __restrict__ k16, ushort* __restrict__ vT, ushort* __restrict__ q16,
            int M, int N, int K) {
  __shared__ __align__(16) ushort sA[2][32 * 64];    // 2 x 4 KiB
  __shared__ __align__(16) ushort sB[2][64 * 64];    // 2 x 8 KiB  (total 24 KiB)
  const int t = threadIdx.x;
  const int w = t >> 6, lane = t & 63;
  const int quad = lane >> 4, l16 = lane & 15;
  const int wn = w * 16;

  // XCD rectangle mapping (bijective; 64 m-tiles split 4 m-groups x 2 n-groups)
  const int bid = blockIdx.x;
  const int half = (N >> 6) >> 1;            // n-tiles per n-group: 9 (gemm1) or 8 (gemm2)
  const int xcd = bid & 7, l = bid >> 3;
  const int mg = xcd >> 1, ng = xcd & 1;
  const int m0 = (mg * 16 + (l & 15)) * 32;
  const int n0 = (ng * half + (l >> 4)) * 64;

  // staging: each async16 covers 8 rows x 64B; source chunk pre-swizzled by row&7.
  const int lr = lane >> 3;
  const int lc = (lane & 7) ^ lr;
  const size_t aBase = (size_t)(m0 + 8 * w + lr) * K + lc * 8;   // wave stages 8 A-rows
  const size_t bBase = (size_t)(n0 + 16 * w + lr) * K + lc * 8;  // wave stages 16 B-rows

  f32x4 acc[2] = {};

  // 3 async16 per wave per tile (1 A + 2 B)
  auto STAGE = [&](int ktile, int b) {
    const size_t koff = (size_t)ktile << 6;
    async16(A + aBase + koff, &sA[b][(8 * w) * 64]);
#pragma unroll
    for (int i = 0; i < 2; ++i)
      async16(B + bBase + (size_t)(8 * i) * K + koff, &sB[b][(16 * w + 8 * i) * 64]);
  };

  // prologue: stage K-tile 0 into buffer 0
  STAGE(0, 0);
  __syncthreads();

  const int NT = K >> 6;   // 16
  for (int kt = 0; kt < NT; ++kt) {
    const int cur = kt & 1;
    // issue next tile's loads FIRST — latency hides under this tile's compute
    if (kt + 1 < NT) STAGE(kt + 1, cur ^ 1);

    f16x8 af[2][2], bf[2];
#pragma unroll
    for (int kst = 0; kst < 2; ++kst) {
      const int cp = ((kst << 2) | quad) ^ (l16 & 7);   // row ≡ l16 (mod 8): 16i,wn ≡ 0 mod 8
#pragma unroll
      for (int i = 0; i < 2; ++i)
        af[kst][i] = *(const f16x8*)(&sA[cur][(16 * i + l16) * 64 + cp * 8]);
      bf[kst] = *(const f16x8*)(&sB[cur][(wn + l16) * 64 + cp * 8]);
    }
#pragma unroll
    for (int kst = 0; kst < 2; ++kst)
#pragma unroll
      for (int i = 0; i < 2; ++i)
        acc[i] = __builtin_amdgcn_mfma_f32_16x16x32_f16(af[kst][i], bf[kst], acc[i], 0, 0, 0);
    __syncthreads();   // drains prefetch (residual only) + protects buffer reuse
  }

  const int cb = n0 + wn;               // lane-uniform column base
  const int col = cb + l16;
#pragma unroll
  for (int i = 0; i < 2; ++i) {
    if (MODE == 0) {
      const float b = bias[col];
#pragma unroll
      for (int r = 0; r < 4; ++r) {
        const int row = m0 + 16 * i + quad * 4 + r;
        Cout[(size_t)row * N + col] = acc[i][r] + b;
      }
    } else {
      const float bscale = (cb >= 2 * DHEAD) ? 8.0f : 1.0f;
      const float b = bias[col] * bscale;
#pragma unroll
      for (int r = 0; r < 4; ++r) {
        const int row = m0 + 16 * i + quad * 4 + r;
        const ushort h = f2h(acc[i][r] + b);
        if (cb >= 2 * DHEAD) {
          q16[(size_t)row * DMODEL + (col - 2 * DHEAD)] = h;
        } else if (cb < DHEAD) {
          k16[(size_t)row * DHEAD + col] = h;
        } else {
          vT[(size_t)(col - DHEAD) * S_LEN + row] = h;
        }
      }
    }
  }
}

// ---------------------------------------------------------------- MFMA flash attention (f16)
// R13-verified body + T5 setprio around the two MFMA clusters (m191: +4-7% on attn
// with independent waves/blocks at differing phases; null only on lockstep GEMM).
// QT=4: one query per wave, 512 blocks, LDS 45 KiB. Key window [jbase, jbase+160),
// jbase=(i0-127)&~7 (clamped 0); max span 138 <= 160. Keys >= S_LEN read allocated
// slack and are masked (exp(-1e30)=0). LDS: Ksw[160][64] (chunk-swizzled,
// global_load_lds), aliased after QK^T by P[64][176]; Vt[64][176]. Fused Wout
// conversion rides the cold K-stage latency shadow (R11).
#define QT 4
#define NTK 10
#define KST 5
#define PSTR 176

__global__ __launch_bounds__(256)
void attn_kernel(const ushort* __restrict__ k16, const ushort* __restrict__ vT,
                 const ushort* __restrict__ q16, ushort* __restrict__ obuf,
                 const float4* __restrict__ wo, ushort4* __restrict__ wo16) {
  __shared__ __align__(16) ushort lds[64 * PSTR + 64 * PSTR];  // 45,056 B
  ushort* Ksw = lds;                  // [160][64] = 20,480 B (inside P region)
  ushort* P   = lds;                  // [64][176] = 22,528 B
  ushort* Vt  = lds + 64 * PSTR;      // [64][176] = 22,528 B

  const int t = threadIdx.x;
  const int i0 = blockIdx.x * QT;
  const int jbase = (i0 >= WIN - 1) ? ((i0 - (WIN - 1)) & ~7) : 0;
  const int w = t >> 6, lane = t & 63;
  const int quad = lane >> 4, l16 = lane & 15;
  const int qg = i0 + w;              // this wave's query

  // ---- stage K: 20 async 1KB instrs, XOR chunk swizzle (chunk c of row r at slot c^(r&7))
#pragma unroll
  for (int i = 0; i < 5; ++i) {
    const int n = 5 * w + i;                 // 0..19, 8 rows each
    const int r = 8 * n + (lane >> 3);
    const int cs = (lane & 7) ^ (r & 7);
    async16(k16 + (size_t)(jbase + r) * DHEAD + cs * 8, &Ksw[n * 512]);
  }
  // ---- fused Wout conversion: 2 float4/thread, overlaps the cold K-stage latency
  {
    const int base = blockIdx.x * 512 + t;   // 512 float4 per block, 262144 total
#pragma unroll
    for (int u = 0; u < 2; ++u) {
      const int idx = base + u * 256;
      const float4 v = wo[idx];
      ushort4 h; h.x = f2h(v.x); h.y = f2h(v.y); h.z = f2h(v.z); h.w = f2h(v.w);
      wo16[idx] = h;
    }
  }
  // ---- stage Vt[64][160] from vT (16B aligned since jbase%8==0)
  {
    const int d = t >> 2, p = t & 3;
#pragma unroll
    for (int it = 0; it < 5; ++it) {
      const int c = p + 4 * it;              // 0..19
      const uint4 raw = *(const uint4*)(vT + (size_t)d * S_LEN + jbase + c * 8);
      *(uint4*)(&Vt[d * PSTR + c * 8]) = raw;
    }
  }
  // ---- Q fragments: lane m-row = head = l16
  f16x8 qf[2];
  {
    const size_t qbase = (size_t)qg * DMODEL + l16 * DHEAD;
#pragma unroll
    for (int kst = 0; kst < 2; ++kst)
      qf[kst] = *(const f16x8*)(q16 + qbase + kst * 32 + quad * 8);
  }
  __syncthreads();

  // ---- QK^T: acc[nt], rows=heads (quad*4+r), cols=keys (nt*16+l16)
  f32x4 acc[NTK] = {};
  __builtin_amdgcn_s_setprio(1);
#pragma unroll
  for (int nt = 0; nt < NTK; ++nt) {
#pragma unroll
    for (int kst = 0; kst < 2; ++kst) {
      const int cp = ((kst << 2) | quad) ^ (l16 & 7);
      const f16x8 bf = *(const f16x8*)(&Ksw[(nt * 16 + l16) * 64 + cp * 8]);
      acc[nt] = __builtin_amdgcn_mfma_f32_16x16x32_f16(qf[kst], bf, acc[nt], 0, 0, 0);
    }
  }
  __builtin_amdgcn_s_setprio(0);
  __syncthreads();  // K region dead; Vt stores drained

  // ---- mask + softmax (regs/shfl over 16 lanes), P -> LDS f16
  float inv_l[4];
#pragma unroll
  for (int nt = 0; nt < NTK; ++nt) {
    const int jg = jbase + nt * 16 + l16;
    const bool valid = (jg <= qg) && (jg > qg - WIN);
#pragma unroll
    for (int r = 0; r < 4; ++r)
      if (!valid) acc[nt][r] = -1e30f;
  }
#pragma unroll
  for (int r = 0; r < 4; ++r) {
    float m = acc[0][r];
#pragma unroll
    for (int nt = 1; nt < NTK; ++nt) m = fmaxf(m, acc[nt][r]);
#pragma unroll
    for (int off = 1; off < 16; off <<= 1) m = fmaxf(m, __shfl_xor(m, off));
    float s = 0.f;
#pragma unroll
    for (int nt = 0; nt < NTK; ++nt) {
      const float e = __expf(acc[nt][r] - m);
      acc[nt][r] = e;
      s += e;
    }
#pragma unroll
    for (int off = 1; off < 16; off <<= 1) s += __shfl_xor(s, off);
    inv_l[r] = 1.0f / s;
  }
  {
    const int mrow0 = w * 16 + quad * 4;
#pragma unroll
    for (int r = 0; r < 4; ++r)
#pragma unroll
      for (int nt = 0; nt < NTK; ++nt)
        P[(mrow0 + r) * PSTR + nt * 16 + l16] = f2h(acc[nt][r]);
  }
  __syncthreads();

  // ---- PV: o[nd], rows=heads, cols=d (nd*16+l16); 5 K-steps over 160 keys
  f32x4 o[4] = {};
  __builtin_amdgcn_s_setprio(1);
#pragma unroll
  for (int kst = 0; kst < KST; ++kst) {
    const f16x8 a = *(const f16x8*)(&P[(w * 16 + l16) * PSTR + kst * 32 + quad * 8]);
#pragma unroll
    for (int nd = 0; nd < 4; ++nd) {
      const f16x8 b = *(const f16x8*)(&Vt[(nd * 16 + l16) * PSTR + kst * 32 + quad * 8]);
      o[nd] = __builtin_amdgcn_mfma_f32_16x16x32_f16(a, b, o[nd], 0, 0, 0);
    }
  }
  __builtin_amdgcn_s_setprio(0);

  // ---- epilogue: normalize, write obuf f16
  {
    const size_t obase = (size_t)qg * DMODEL;
#pragma unroll
    for (int nd = 0; nd < 4; ++nd)
#pragma unroll
      for (int r = 0; r < 4; ++r) {
        const int col = (quad * 4 + r) * DHEAD + nd * 16 + l16;
        obuf[obase + col] = f2h(o[nd][r] * inv_l[r]);
      }
  }
}

// ---------------------------------------------------------------- launch
extern "C" void kernel_launch(void* const* d_in, const int* in_sizes, int n_in,
                              void* d_out, int out_size, void* d_ws, size_t ws_size,
                              hipStream_t stream) {
  const float* x    = (const float*)d_in[0];
  const float* Wqkv = (const float*)d_in[1];
  const float* bqkv = (const float*)d_in[2];
  const float* Wout = (const float*)d_in[3];
  const float* bout = (const float*)d_in[4];
  float* out = (float*)d_out;

  char* w = (char*)d_ws;
  ushort* x16  = (ushort*)(w + 0);          // 4,194,304 B
  ushort* w16  = (ushort*)(w + 4194304);    // 2,359,296 B
  ushort* wo16 = (ushort*)(w + 6553600);    // 2,097,152 B
  ushort* k16  = (ushort*)(w + 8650752);    // 270,336 B  (2112 rows x 64; rows >=2048 stay 0xAA)
  ushort* vT   = (ushort*)(w + 8921088);    // 270,336 B  (64 x 2048 + 8KB slack, stays 0xAA)
  ushort* q16  = (ushort*)(w + 9191424);    // 4,194,304 B
  ushort* obuf = (ushort*)(w + 13385728);   // 4,194,304 B   (total ~17.6 MB)

  convert_kernel<<<3200, 256, 0, stream>>>(
      (const float4*)x, (const float4*)Wqkv, (ushort4*)x16, (ushort4*)w16);

  gemm32<1><<<1152, 256, 0, stream>>>(x16, w16, bqkv, nullptr, k16, vT, q16,
                                      S_LEN, NQKV, DMODEL);

  attn_kernel<<<S_LEN / QT, 256, 0, stream>>>(k16, vT, q16, obuf,
                                              (const float4*)Wout, (ushort4*)wo16);

  gemm32<0><<<1024, 256, 0, stream>>>(obuf, wo16, bout, out, nullptr, nullptr, nullptr,
                                      S_LEN, DMODEL, DMODEL);
}